// Round 3
// baseline (99.645 us; speedup 1.0000x reference)
//
#include <hip/hip_runtime.h>

#define THREADS 256
#define TB 64           // rows per block (4 waves x 16)
#define DIN 60
#define HN 256
#define DOUT 360
#define NT2 23          // GEMM2 N tiles (23*16 = 368 padded cols)
#define KT2 8           // GEMM2 K tiles (256/32)

typedef __attribute__((ext_vector_type(8))) short short8;
typedef __attribute__((ext_vector_type(4))) float f32x4;
typedef __attribute__((ext_vector_type(2))) float f32x2;
typedef __attribute__((ext_vector_type(4))) unsigned int u32x4;

// d_ws layout (bytes); total 231424 B
#define WS_CBF   0            // 2048 * 16 B = 32768  (centres bf16, swizzled)
#define WS_CN    32768        // 256 * float2 {c2, -sigma^2*log2e} = 2048 B
#define WS_W2    34816        // 8 kt * 1536 * 16 B = 196608 (W2 bf16, permuted+swizzled)

__device__ __forceinline__ short bf16_bits(float f) {
    union { float f; unsigned u; } v; v.f = f;
    unsigned r = (v.u + 0x7FFFu + ((v.u >> 16) & 1u)) >> 16;   // RNE
    return (short)(unsigned short)r;
}

__device__ __forceinline__ void gload16(const void* g, void* lds) {
    __builtin_amdgcn_global_load_lds(
        (const __attribute__((address_space(1))) unsigned int*)(uintptr_t)g,
        (__attribute__((address_space(3))) unsigned int*)(unsigned int)(uintptr_t)lds,
        16, 0, 0);
}

// ---------------- prep: convert/permute/swizzle constants into ws ----------------
__global__ void prep(const float* __restrict__ centres, const float* __restrict__ sigmas,
                     const float* __restrict__ W2, short* __restrict__ ws)
{
    int t = blockIdx.x * 256 + threadIdx.x;
    if (t < 12288) {
        // W2 k-slices: [kt][row 0..383][phys chunk p 0..3] of short8
        int kt = t / 1536, rem = t % 1536;
        int row = rem >> 2, p = rem & 3;
        int c = p ^ ((row >> 1) & 3);
        short8 v = {0,0,0,0,0,0,0,0};
        if (row < DOUT) {
            int rr = row / 12, jj = row % 12;
            int f = rr / 3, kk = rr % 3;
            int o = f * 36 + jj * 3 + kk;              // fold output col permutation
            const float* src = W2 + o * HN + kt * 32 + c * 8;
            #pragma unroll
            for (int i = 0; i < 8; ++i) v[i] = bf16_bits(src[i]);
        }
        *(short8*)(ws + (WS_W2 / 2) + t * 8) = v;
    } else if (t < 14336) {
        // centres bf16: [row 0..255][phys chunk p 0..7], k padded 60->64
        int j = t - 12288;
        int row = j >> 3, p = j & 7;
        int c = p ^ (row & 7);
        short8 v = {0,0,0,0,0,0,0,0};
        #pragma unroll
        for (int i = 0; i < 8; ++i) {
            int k = c * 8 + i;
            if (k < DIN) v[i] = bf16_bits(centres[row * DIN + k]);
        }
        *(short8*)(ws + (WS_CBF / 2) + j * 8) = v;
    } else if (t < 14592) {
        int i = t - 14336;
        const float* cr = centres + i * DIN;
        float s = 0.f;
        #pragma unroll
        for (int d = 0; d < DIN; ++d) s = fmaf(cr[d], cr[d], s);
        float sg = sigmas[i];
        f32x2 v; v[0] = s; v[1] = -sg * sg * 1.44269504088896340736f;
        *(f32x2*)(ws + (WS_CN / 2) + i * 4) = v;
    }
}

// ---------------- main fused kernel ----------------
__global__ __launch_bounds__(THREADS, 3)
void rbf_main(const float* __restrict__ x, const short* __restrict__ ws,
              float* __restrict__ out)
{
    // union: [0,32K) cbf during GEMM1, then w2s dbuf 2x24K in [0,48K); cns at 48K
    __shared__ __attribute__((aligned(16))) char smem[49152 + 2048];
    short8* const cbf = (short8*)smem;
    const f32x2* const cns = (const f32x2*)(smem + 49152);

    const int tid  = threadIdx.x;
    const int w    = tid >> 6;
    const int lane = tid & 63;
    const int l15  = lane & 15;
    const int g    = lane >> 4;
    const int b0   = blockIdx.x * TB;

    // ---- prologue: async stage centres(bf16) + cn table ----
    #pragma unroll
    for (int it = 0; it < 8; ++it)
        gload16(ws + (WS_CBF / 2) + (it * THREADS + tid) * 8, smem + (it * THREADS + tid) * 16);
    if (tid < 128)
        gload16(ws + (WS_CN / 2) + tid * 8, smem + 49152 + tid * 16);

    // ---- per-lane x fragment: B-frag for swapped GEMM1 (n=row=l15, k=g*8+j) ----
    const float* xr = x + (size_t)(b0 + w * 16 + l15) * DIN;
    f32x4 xa[2][2];
    #pragma unroll
    for (int kt = 0; kt < 2; ++kt) {
        int k0 = kt * 32 + g * 8;
        xa[kt][0] = *(const f32x4*)(xr + k0);
        if (k0 + 4 < DIN) xa[kt][1] = *(const f32x4*)(xr + k0 + 4);
        else              xa[kt][1] = (f32x4){0.f, 0.f, 0.f, 0.f};
    }
    float p2 = 0.f;
    #pragma unroll
    for (int kt = 0; kt < 2; ++kt)
        #pragma unroll
        for (int h = 0; h < 2; ++h)
            #pragma unroll
            for (int i = 0; i < 4; ++i) p2 = fmaf(xa[kt][h][i], xa[kt][h][i], p2);
    p2 += __shfl_xor(p2, 16);
    p2 += __shfl_xor(p2, 32);
    const float x2v = p2;              // x2 of row l15, in-register (no LDS)

    short8 xb[2];
    #pragma unroll
    for (int kt = 0; kt < 2; ++kt) {
        short8 a;
        #pragma unroll
        for (int i = 0; i < 4; ++i) a[i]     = bf16_bits(xa[kt][0][i]);
        #pragma unroll
        for (int i = 0; i < 4; ++i) a[4 + i] = bf16_bits(xa[kt][1][i]);
        xb[kt] = a;
    }

    __syncthreads();   // cbf + cns staged

    // ---- GEMM1 (swapped): S^T tiles, D col=l15=batch row, reg (g,r) -> h=nt*16+g*4+r ----
    f32x4 acc1[16];
    #pragma unroll
    for (int nt = 0; nt < 16; ++nt) acc1[nt] = (f32x4){0.f, 0.f, 0.f, 0.f};
    #pragma unroll
    for (int nt = 0; nt < 16; ++nt) {
        int row = nt * 16 + l15;
        #pragma unroll
        for (int kt = 0; kt < 2; ++kt) {
            short8 cf = cbf[row * 8 + ((kt * 4 + g) ^ (row & 7))];
            acc1[nt] = __builtin_amdgcn_mfma_f32_16x16x32_bf16(cf, xb[kt], acc1[nt], 0, 0, 0);
        }
    }

    __syncthreads();   // cbf dead -> its LDS becomes the w2s double-buffer

    // ---- issue W2 slice kt=0 into buffer 0 (latency hides under phi) ----
    #pragma unroll
    for (int it = 0; it < 6; ++it)
        gload16(ws + (WS_W2 / 2) + (it * THREADS + tid) * 8, smem + (it * THREADS + tid) * 16);

    // ---- phi = exp2(ns2*(x2 + c2 - 2S)) packed to bf16 word-pairs ----
    unsigned pw[16][2];
    #pragma unroll
    for (int nt = 0; nt < 16; ++nt) {
        unsigned ph[4];
        #pragma unroll
        for (int r = 0; r < 4; ++r) {
            f32x2 cn = cns[nt * 16 + g * 4 + r];
            float d2 = fmaxf(x2v + cn[0] - 2.f * acc1[nt][r], 0.f);
            ph[r] = (unsigned)(unsigned short)bf16_bits(exp2f(cn[1] * d2));
        }
        pw[nt][0] = ph[0] | (ph[1] << 16);
        pw[nt][1] = ph[2] | (ph[3] << 16);
    }

    __syncthreads();   // w2s[0] landed

    // ---- GEMM2: out = phi . W2^T, A-frag built by intra-wave shuffle transpose ----
    f32x4 acc2[NT2];
    #pragma unroll
    for (int nt = 0; nt < NT2; ++nt) acc2[nt] = (f32x4){0.f, 0.f, 0.f, 0.f};

    const int s0 = l15 + ((g & 1) << 5);   // source lane (g_s even)
    const bool hi = (g >= 2);              // which source tile (2kt / 2kt+1)

    #pragma unroll
    for (int kt = 0; kt < KT2; ++kt) {
        if (kt < KT2 - 1) {   // prefetch next k-slice into other buffer
            #pragma unroll
            for (int it = 0; it < 6; ++it)
                gload16(ws + (WS_W2 / 2) + ((kt + 1) * 1536 + it * THREADS + tid) * 8,
                        smem + (((kt & 1) ^ 1) * 24576) + (it * THREADS + tid) * 16);
        }
        // A-frag: lane (l15,g) needs phi[row=l15][h=kt*32+g*8+j], j=0..7
        int a0 = __shfl((int)pw[2*kt][0], s0);      int b0_ = __shfl((int)pw[2*kt+1][0], s0);
        int a1 = __shfl((int)pw[2*kt][1], s0);      int b1_ = __shfl((int)pw[2*kt+1][1], s0);
        int a2 = __shfl((int)pw[2*kt][0], s0 + 16); int b2_ = __shfl((int)pw[2*kt+1][0], s0 + 16);
        int a3 = __shfl((int)pw[2*kt][1], s0 + 16); int b3_ = __shfl((int)pw[2*kt+1][1], s0 + 16);
        union { u32x4 u; short8 s; } afu;
        afu.u[0] = (unsigned)(hi ? b0_ : a0);
        afu.u[1] = (unsigned)(hi ? b1_ : a1);
        afu.u[2] = (unsigned)(hi ? b2_ : a2);
        afu.u[3] = (unsigned)(hi ? b3_ : a3);

        const short8* wb = (const short8*)(smem + (kt & 1) * 24576);
        #pragma unroll
        for (int nt = 0; nt < NT2; ++nt) {
            int row = nt * 16 + l15;
            short8 bf = wb[row * 4 + (g ^ ((row >> 1) & 3))];
            acc2[nt] = __builtin_amdgcn_mfma_f32_16x16x32_bf16(afu.s, bf, acc2[nt], 0, 0, 0);
        }
        if (kt < KT2 - 1) __syncthreads();   // prefetch landed; buffer reuse safe
    }

    // ---- store (columns already in final permuted order) ----
    const int orow = b0 + w * 16 + g * 4;
    #pragma unroll
    for (int nt = 0; nt < NT2; ++nt) {
        int col = nt * 16 + l15;
        if (col < DOUT) {
            #pragma unroll
            for (int r = 0; r < 4; ++r)
                out[(size_t)(orow + r) * DOUT + col] = acc2[nt][r];
        }
    }
}

extern "C" void kernel_launch(void* const* d_in, const int* in_sizes, int n_in,
                              void* d_out, int out_size, void* d_ws, size_t ws_size,
                              hipStream_t stream) {
    const float* x       = (const float*)d_in[0];
    const float* centres = (const float*)d_in[1];
    const float* sigmas  = (const float*)d_in[2];
    const float* W2      = (const float*)d_in[3];
    float* out = (float*)d_out;
    short* ws  = (short*)d_ws;                  // needs 231424 B
    const int Brows = in_sizes[0] / DIN;        // 131072

    prep<<<dim3(57), dim3(256), 0, stream>>>(centres, sigmas, W2, ws);
    rbf_main<<<dim3(Brows / TB), dim3(THREADS), 0, stream>>>(x, ws, out);
}